// Round 9
// baseline (221.697 us; speedup 1.0000x reference)
//
#include <hip/hip_runtime.h>
#include <hip/hip_bf16.h>

typedef unsigned short ushort_t;
typedef unsigned int uint_t;
using f32x4  = __attribute__((ext_vector_type(4))) float;
using short8 = __attribute__((ext_vector_type(8))) short;

#define NN 8192
#define INVLN2 1.4426950408889634f

__device__ __forceinline__ ushort_t f2bf(float f) {
  uint_t u = __builtin_bit_cast(uint_t, f);
  u += 0x7FFFu + ((u >> 16) & 1u);   // RNE
  return (ushort_t)(u >> 16);
}

__device__ __forceinline__ float fexp2(float x) {
  float r; asm("v_exp_f32 %0, %1" : "=v"(r) : "v"(x)); return r;
}

// ---------------------------------------------------------------------------
// K1: Xp = X @ W  -> XpT bf16 [2*64][8192] (row = h*64+c), x0[N][2], x1T[2][N]
// x0/x1 pre-scaled by 1/ln2 (lrelu positively homogeneous -> exp via exp2).
// ---------------------------------------------------------------------------
__global__ __launch_bounds__(256, 2) void k1_project(
    const float* __restrict__ X, const float* __restrict__ W,
    const float* __restrict__ attn,
    ushort_t* __restrict__ XpT, float* __restrict__ x0g, float* __restrict__ x1g)
{
  __shared__ float    Xl[32][128];      // 16 KB
  __shared__ ushort_t XpL[128][56];     // 14 KB
  __shared__ float    P0[128][33];
  __shared__ float    P1[128][33];
  const int t  = threadIdx.x;
  const int nb = blockIdx.x * 32;

  #pragma unroll
  for (int r = 0; r < 4; ++r) {
    int chunk = r * 256 + t;
    ((float4*)(&Xl[0][0]))[chunk] = ((const float4*)(X + (size_t)nb * 128))[chunk];
  }
  __syncthreads();

  const int p = t & 127;
  const int g = t >> 7;
  const int h = p & 1, c = p >> 1;

  float acc[16];
  #pragma unroll
  for (int n = 0; n < 16; ++n) acc[n] = 0.f;

  for (int jc = 0; jc < 4; ++jc) {
    float wreg[32];
    #pragma unroll
    for (int jj = 0; jj < 32; ++jj) wreg[jj] = W[(jc * 32 + jj) * 128 + p];
    #pragma unroll
    for (int n = 0; n < 16; ++n) {
      const float4* xr = (const float4*)(&Xl[g * 16 + n][jc * 32]);
      float s = acc[n];
      #pragma unroll
      for (int q = 0; q < 8; ++q) {
        float4 xv = xr[q];
        s += xv.x * wreg[q*4+0] + xv.y * wreg[q*4+1] + xv.z * wreg[q*4+2] + xv.w * wreg[q*4+3];
      }
      acc[n] = s;
    }
  }

  const float a0 = attn[p] * INVLN2;
  const float a1 = attn[128 + p] * INVLN2;
  const int   row = h * 64 + c;
  #pragma unroll
  for (int n = 0; n < 16; ++n) {
    P0[p][g * 16 + n]  = acc[n] * a0;
    P1[p][g * 16 + n]  = acc[n] * a1;
    XpL[row][g * 16 + n] = f2bf(acc[n]);
  }
  __syncthreads();

  if (t < 128) {
    ushort_t* dst = XpT + (size_t)t * NN + nb;
    const uint4* src = (const uint4*)(&XpL[t][0]);
    ((uint4*)dst)[0] = src[0];
    ((uint4*)dst)[1] = src[1];
    ((uint4*)dst)[2] = src[2];
    ((uint4*)dst)[3] = src[3];
  }
  if (t < 64) {
    int node = t >> 1, hh = t & 1;
    float s0 = 0.f, s1 = 0.f;
    #pragma unroll
    for (int cc = 0; cc < 64; ++cc) {
      s0 += P0[cc * 2 + hh][node];
      s1 += P1[cc * 2 + hh][node];
    }
    x0g[(nb + node) * 2 + hh] = s0;
    x1g[hh * NN + nb + node]  = s1;
  }
}

// ---------------------------------------------------------------------------
// K2: wave-private, ZERO barriers. 4 waves = (head hw, k-half ksh).
// Each wave: 32 rows x 64 ch x (KS/2) k. P computed in-register in the MFMA
// A-frag layout (row=lane&15, k=(lane>>4)*8+j — verified r4/r5). B staged
// per-wave-privately (4 KB: its head+k-half) into 80B-padded dbuf LDS tile;
// line-perfect global loads + ds_write (T14 split: load early, write late).
// A: 2-deep named U/V refill. k-half partials -> split sp2 = sp*2+ksh.
// ---------------------------------------------------------------------------
__global__ __launch_bounds__(256, 4) void k2_main(
    const float* __restrict__ A, const ushort_t* __restrict__ XpT,
    const float* __restrict__ x0g, const float* __restrict__ x1g,
    float* __restrict__ part, float* __restrict__ denp,
    const int S, const int KS)
{
  __shared__ __align__(16) char Bl[4][2][5120];   // 40 KB: per-wave dbuf tiles
  const int t  = threadIdx.x;
  const int b  = blockIdx.x;
  const int rb = b / S, sp = b % S;
  const int ib = rb * 32;
  const int lane = t & 63, w = t >> 6;
  const int hw  = w & 1;          // head
  const int ksh = w >> 1;         // k-half
  const int KS2 = KS >> 1;
  const int kw  = sp * KS + ksh * KS2;   // wave k-base
  const int nt  = KS2 >> 5;              // bodies, k-step 32
  const int l15 = lane & 15, lg = lane >> 4;
  const int sp2 = sp * 2 + ksh;

  const float x00 = x0g[(ib + l15) * 2 + hw];
  const float x01 = x0g[(ib + 16 + l15) * 2 + hw];

  const float*    Ar0  = A   + (size_t)(ib + l15) * NN + kw + lg * 8;
  const float*    Ar1  = A   + (size_t)(ib + 16 + l15) * NN + kw + lg * 8;
  const float*    Xq   = x1g + (size_t)hw * NN + kw + lg * 8;
  const ushort_t* Bsrc = XpT + (size_t)(hw * 64 + (lane >> 2)) * NN + kw + (lane & 3) * 8;

  char* Bme = &Bl[w][0][0];
  const int wOff = (lane >> 2) * 80 + (lane & 3) * 16;
  int roff[4];
  #pragma unroll
  for (int cb = 0; cb < 4; ++cb) roff[cb] = (cb * 16 + l15) * 80 + lg * 16;

  f32x4 acc[2][4] = {};
  float den0 = 0.f, den1 = 0.f;

  // ---- prologue: stage B(0) -> buf0; A sets U(tile0), V(tile1) ----
  {
    uint4 s0 = *(const uint4*)(Bsrc);
    uint4 s1 = *(const uint4*)(Bsrc + (size_t)16 * NN);
    uint4 s2 = *(const uint4*)(Bsrc + (size_t)32 * NN);
    uint4 s3 = *(const uint4*)(Bsrc + (size_t)48 * NN);
    *(uint4*)(Bme + wOff)        = s0;
    *(uint4*)(Bme + 1280 + wOff) = s1;
    *(uint4*)(Bme + 2560 + wOff) = s2;
    *(uint4*)(Bme + 3840 + wOff) = s3;
  }
  float4 Ua0 = *(const float4*)(Ar0);
  float4 Ua1 = *(const float4*)(Ar0 + 4);
  float4 Ub0 = *(const float4*)(Ar1);
  float4 Ub1 = *(const float4*)(Ar1 + 4);
  float4 Va0 = *(const float4*)(Ar0 + 32);
  float4 Va1 = *(const float4*)(Ar0 + 36);
  float4 Vb0 = *(const float4*)(Ar1 + 32);
  float4 Vb1 = *(const float4*)(Ar1 + 36);

#define KBODY(p0a, p0b, p1a, p1b, TT, BUF)                                   \
  {                                                                          \
    const int t_  = (TT);                                                    \
    const int rtB = (t_ + 1 < nt) ? (t_ + 1) : (nt - 1);                     \
    const int rtA = (t_ + 2 < nt) ? (t_ + 2) : (nt - 1);                     \
    /* 1. issue B(t+1) loads (line-perfect 16 rows x 64B per instr) */       \
    uint4 s0 = *(const uint4*)(Bsrc + (rtB << 5));                           \
    uint4 s1 = *(const uint4*)(Bsrc + (size_t)16 * NN + (rtB << 5));         \
    uint4 s2 = *(const uint4*)(Bsrc + (size_t)32 * NN + (rtB << 5));         \
    uint4 s3 = *(const uint4*)(Bsrc + (size_t)48 * NN + (rtB << 5));         \
    /* 2. x1 (broadcast) */                                                  \
    float4 xv0 = *(const float4*)(Xq + (t_ << 5));                           \
    float4 xv1 = *(const float4*)(Xq + (t_ << 5) + 4);                       \
    /* 3. P compute -> A-frags (in-register) */                              \
    float pr0[8], pr1[8];                                                    \
    { float xa[8] = {xv0.x,xv0.y,xv0.z,xv0.w,xv1.x,xv1.y,xv1.z,xv1.w};       \
      float a0[8] = {p0a.x,p0a.y,p0a.z,p0a.w,p0b.x,p0b.y,p0b.z,p0b.w};       \
      float a1[8] = {p1a.x,p1a.y,p1a.z,p1a.w,p1b.x,p1b.y,p1b.z,p1b.w};       \
      _Pragma("unroll")                                                      \
      for (int j = 0; j < 8; ++j) {                                          \
        float s0_ = x00 + xa[j];                                             \
        float e0_ = fexp2(fmaxf(s0_, 0.2f * s0_));                           \
        pr0[j] = a0[j] * e0_; den0 += pr0[j];                                \
        float s1_ = x01 + xa[j];                                             \
        float e1_ = fexp2(fmaxf(s1_, 0.2f * s1_));                           \
        pr1[j] = a1[j] * e1_; den1 += pr1[j];                                \
      } }                                                                    \
    uint_t c0,c1,c2,c3,c4,c5,c6,c7;                                          \
    asm("v_cvt_pk_bf16_f32 %0, %1, %2" : "=v"(c0) : "v"(pr0[0]), "v"(pr0[1])); \
    asm("v_cvt_pk_bf16_f32 %0, %1, %2" : "=v"(c1) : "v"(pr0[2]), "v"(pr0[3])); \
    asm("v_cvt_pk_bf16_f32 %0, %1, %2" : "=v"(c2) : "v"(pr0[4]), "v"(pr0[5])); \
    asm("v_cvt_pk_bf16_f32 %0, %1, %2" : "=v"(c3) : "v"(pr0[6]), "v"(pr0[7])); \
    asm("v_cvt_pk_bf16_f32 %0, %1, %2" : "=v"(c4) : "v"(pr1[0]), "v"(pr1[1])); \
    asm("v_cvt_pk_bf16_f32 %0, %1, %2" : "=v"(c5) : "v"(pr1[2]), "v"(pr1[3])); \
    asm("v_cvt_pk_bf16_f32 %0, %1, %2" : "=v"(c6) : "v"(pr1[4]), "v"(pr1[5])); \
    asm("v_cvt_pk_bf16_f32 %0, %1, %2" : "=v"(c7) : "v"(pr1[6]), "v"(pr1[7])); \
    uint4 uv0; uv0.x = c0; uv0.y = c1; uv0.z = c2; uv0.w = c3;               \
    uint4 uv1; uv1.x = c4; uv1.y = c5; uv1.z = c6; uv1.w = c7;               \
    short8 af0 = __builtin_bit_cast(short8, uv0);                            \
    short8 af1 = __builtin_bit_cast(short8, uv1);                            \
    /* 4. refill this A set with tile t+2 */                                 \
    p0a = *(const float4*)(Ar0 + (rtA << 5));                                \
    p0b = *(const float4*)(Ar0 + (rtA << 5) + 4);                            \
    p1a = *(const float4*)(Ar1 + (rtA << 5));                                \
    p1b = *(const float4*)(Ar1 + (rtA << 5) + 4);                            \
    /* 5. MFMA from private buf (written last body; same-wave order) */      \
    { const char* rb_ = Bme + (BUF) * 5120;                                  \
      _Pragma("unroll")                                                      \
      for (int cb = 0; cb < 4; ++cb) {                                       \
        short8 bv = *(const short8*)(rb_ + roff[cb]);                        \
        acc[0][cb] = __builtin_amdgcn_mfma_f32_16x16x32_bf16(af0, bv, acc[0][cb], 0, 0, 0); \
        acc[1][cb] = __builtin_amdgcn_mfma_f32_16x16x32_bf16(af1, bv, acc[1][cb], 0, 0, 0); \
      } }                                                                    \
    /* 6. write staged B(t+1) -> other private buf */                        \
    { char* wb_ = Bme + (((BUF) ^ 1) * 5120);                                \
      *(uint4*)(wb_ + wOff)        = s0;                                     \
      *(uint4*)(wb_ + 1280 + wOff) = s1;                                     \
      *(uint4*)(wb_ + 2560 + wOff) = s2;                                     \
      *(uint4*)(wb_ + 3840 + wOff) = s3; }                                   \
  }

  for (int tt = 0; tt < nt; tt += 2) {
    KBODY(Ua0, Ua1, Ub0, Ub1, tt,     0)
    KBODY(Va0, Va1, Vb0, Vb1, tt + 1, 1)
  }
#undef KBODY

  // --- den: sum the 4 k-groups (lanes xor 16, 32 share a row) ---
  den0 += __shfl_xor(den0, 16);
  den0 += __shfl_xor(den0, 32);
  den1 += __shfl_xor(den1, 16);
  den1 += __shfl_xor(den1, 32);
  if (lane < 16) {
    denp[((size_t)sp2 * NN + ib + lane) * 2 + hw]      = den0;
    denp[((size_t)sp2 * NN + ib + 16 + lane) * 2 + hw] = den1;
  }

  // --- partial numerators (C/D: col=lane&15, row=(lane>>4)*4+r) ---
  float* pbase = part + ((size_t)sp2 * NN + ib) * 128;
  #pragma unroll
  for (int iw = 0; iw < 2; ++iw)
    #pragma unroll
    for (int cb = 0; cb < 4; ++cb)
      #pragma unroll
      for (int r = 0; r < 4; ++r) {
        int lr  = iw * 16 + lg * 4 + r;
        int col = hw * 64 + cb * 16 + l15;
        pbase[lr * 128 + col] = acc[iw][cb][r];
      }
}

// ---------------------------------------------------------------------------
// K3: combine S2 splits, normalize, add bias.
// ---------------------------------------------------------------------------
__global__ __launch_bounds__(256) void k3_finish(
    const float* __restrict__ part, const float* __restrict__ denp,
    const float* __restrict__ bias, float* __restrict__ out, const int S2)
{
  const int idx = blockIdx.x * 256 + threadIdx.x;
  const int i  = idx >> 5;
  const int hc = (idx & 31) * 4;
  const int h  = hc >> 6;
  float4 s; s.x = s.y = s.z = s.w = 0.f;
  float d = 0.f;
  for (int sp = 0; sp < S2; ++sp) {
    float4 v = *(const float4*)(part + ((size_t)sp * NN + i) * 128 + hc);
    s.x += v.x; s.y += v.y; s.z += v.z; s.w += v.w;
    d += denp[((size_t)sp * NN + i) * 2 + h];
  }
  const float sc = 1.f / (d + 0.001f);
  float4 bv = *(const float4*)(bias + hc);
  float4 o;
  o.x = s.x * sc + bv.x;
  o.y = s.y * sc + bv.y;
  o.z = s.z * sc + bv.z;
  o.w = s.w * sc + bv.w;
  *(float4*)(out + (size_t)i * 128 + hc) = o;
}

extern "C" void kernel_launch(void* const* d_in, const int* in_sizes, int n_in,
                              void* d_out, int out_size, void* d_ws, size_t ws_size,
                              hipStream_t stream) {
  const float* A    = (const float*)d_in[0];
  const float* X    = (const float*)d_in[1];
  const float* W    = (const float*)d_in[2];
  const float* attn = (const float*)d_in[3];
  const float* bias = (const float*)d_in[4];
  float* out = (float*)d_out;

  char* ws = (char*)d_ws;
  size_t off = 0;
  ushort_t* XpT = (ushort_t*)(ws + off); off += (size_t)128 * NN * sizeof(ushort_t);
  float* x0g = (float*)(ws + off); off += (size_t)NN * 2 * sizeof(float);
  float* x1g = (float*)(ws + off); off += (size_t)2 * NN * sizeof(float);

  int S = 4;
  while (S > 1) {
    size_t s2 = (size_t)S * 2;
    size_t need = off + s2 * NN * 2 * 4 + s2 * NN * 128 * 4;
    if (need <= ws_size) break;
    S >>= 1;
  }
  const int S2 = S * 2;
  float* denp = (float*)(ws + off); off += (size_t)S2 * NN * 2 * sizeof(float);
  float* part = (float*)(ws + off);
  const int KS = NN / S;

  k1_project<<<256, 256, 0, stream>>>(X, W, attn, XpT, x0g, x1g);
  k2_main<<<(NN / 32) * S, 256, 0, stream>>>(A, XpT, x0g, x1g, part, denp, S, KS);
  k3_finish<<<1024, 256, 0, stream>>>(part, denp, bias, out, S2);
}

// Round 10
// 133.354 us; speedup vs baseline: 1.6625x; 1.6625x over previous
//
#include <hip/hip_runtime.h>
#include <hip/hip_bf16.h>

typedef unsigned short ushort_t;
typedef unsigned int uint_t;
using f32x4  = __attribute__((ext_vector_type(4))) float;
using short8 = __attribute__((ext_vector_type(8))) short;

#define NN 8192
#define INVLN2 1.4426950408889634f

__device__ __forceinline__ ushort_t f2bf(float f) {
  uint_t u = __builtin_bit_cast(uint_t, f);
  u += 0x7FFFu + ((u >> 16) & 1u);   // RNE
  return (ushort_t)(u >> 16);
}

__device__ __forceinline__ float fexp2(float x) {
  float r; asm("v_exp_f32 %0, %1" : "=v"(r) : "v"(x)); return r;
}

__device__ __forceinline__ void gload16(const void* g, void* l) {
  __builtin_amdgcn_global_load_lds(
      (const __attribute__((address_space(1))) void*)g,
      (__attribute__((address_space(3))) void*)l, 16, 0, 0);
}

// ---------------------------------------------------------------------------
// K1: Xp = X @ W  -> XpT bf16 [2*64][8192] (row = h*64+c), x0[N][2], x1T[2][N]
// x0/x1 pre-scaled by 1/ln2 (lrelu positively homogeneous -> exp via exp2).
// (verified r8/r9)
// ---------------------------------------------------------------------------
__global__ __launch_bounds__(256, 2) void k1_project(
    const float* __restrict__ X, const float* __restrict__ W,
    const float* __restrict__ attn,
    ushort_t* __restrict__ XpT, float* __restrict__ x0g, float* __restrict__ x1g)
{
  __shared__ float    Xl[32][128];      // 16 KB
  __shared__ ushort_t XpL[128][56];     // 14 KB
  __shared__ float    P0[128][33];
  __shared__ float    P1[128][33];
  const int t  = threadIdx.x;
  const int nb = blockIdx.x * 32;

  #pragma unroll
  for (int r = 0; r < 4; ++r) {
    int chunk = r * 256 + t;
    ((float4*)(&Xl[0][0]))[chunk] = ((const float4*)(X + (size_t)nb * 128))[chunk];
  }
  __syncthreads();

  const int p = t & 127;
  const int g = t >> 7;
  const int h = p & 1, c = p >> 1;

  float acc[16];
  #pragma unroll
  for (int n = 0; n < 16; ++n) acc[n] = 0.f;

  for (int jc = 0; jc < 4; ++jc) {
    float wreg[32];
    #pragma unroll
    for (int jj = 0; jj < 32; ++jj) wreg[jj] = W[(jc * 32 + jj) * 128 + p];
    #pragma unroll
    for (int n = 0; n < 16; ++n) {
      const float4* xr = (const float4*)(&Xl[g * 16 + n][jc * 32]);
      float s = acc[n];
      #pragma unroll
      for (int q = 0; q < 8; ++q) {
        float4 xv = xr[q];
        s += xv.x * wreg[q*4+0] + xv.y * wreg[q*4+1] + xv.z * wreg[q*4+2] + xv.w * wreg[q*4+3];
      }
      acc[n] = s;
    }
  }

  const float a0 = attn[p] * INVLN2;
  const float a1 = attn[128 + p] * INVLN2;
  const int   row = h * 64 + c;
  #pragma unroll
  for (int n = 0; n < 16; ++n) {
    P0[p][g * 16 + n]  = acc[n] * a0;
    P1[p][g * 16 + n]  = acc[n] * a1;
    XpL[row][g * 16 + n] = f2bf(acc[n]);
  }
  __syncthreads();

  if (t < 128) {
    ushort_t* dst = XpT + (size_t)t * NN + nb;
    const uint4* src = (const uint4*)(&XpL[t][0]);
    ((uint4*)dst)[0] = src[0];
    ((uint4*)dst)[1] = src[1];
    ((uint4*)dst)[2] = src[2];
    ((uint4*)dst)[3] = src[3];
  }
  if (t < 64) {
    int node = t >> 1, hh = t & 1;
    float s0 = 0.f, s1 = 0.f;
    #pragma unroll
    for (int cc = 0; cc < 64; ++cc) {
      s0 += P0[cc * 2 + hh][node];
      s1 += P1[cc * 2 + hh][node];
    }
    x0g[(nb + node) * 2 + hh] = s0;
    x1g[hh * NN + nb + node]  = s1;
  }
}

// ---------------------------------------------------------------------------
// K2: r3 structure, K-step 32. LDS = Pl 4 KB (single) + Bl 16 KB (dbuf) =
// 20 KB -> 5 blocks/CU (launch_bounds 256,5). Barriers + counted vmcnt(5)
// exactly as r3 (5 vmem/body = 3 reg prefetch + 2 gload_lds). Swizzle mask
// (row&3)<<4 for 64B rows, inverse-applied to gload source. S=8: split sp
// lands on XCD sp -> XpT slice L2-local.
// ---------------------------------------------------------------------------
__global__ __launch_bounds__(256, 5) void k2_main(
    const float* __restrict__ A, const ushort_t* __restrict__ XpT,
    const float* __restrict__ x0g, const float* __restrict__ x1g,
    float* __restrict__ part, float* __restrict__ denp,
    const int S, const int KS)
{
  __shared__ __align__(16) ushort_t Pl[64 * 32];        // 4 KB single
  __shared__ __align__(16) ushort_t Bl[2 * 128 * 32];   // 16 KB double buffer
  const int t  = threadIdx.x;
  const int b  = blockIdx.x;
  const int rb = b / S, sp = b % S;
  const int ib = rb * 32;
  const int k0 = sp * KS;
  const int lane = t & 63, w = t >> 6;
  const int hw = w & 1, iw = w >> 1;    // wave: head, 16-row block
  const int pr = t >> 3;                // P-compute row 0..31
  const int pk = (t & 7) * 4;           // P-compute k elem 0..28

  const float2 x0v = *(const float2*)(x0g + (ib + pr) * 2);

  // B staging: chunk c = q*256+t; row=c>>2, granule jj=c&3 (16B granules,
  // 4 per 64B row). LDS linear dest; source granule inverse-swizzled.
  int srcOff[2], ldsOff[2];
  #pragma unroll
  for (int q = 0; q < 2; ++q) {
    int c = q * 256 + t;
    int cr = c >> 2, jj = c & 3;
    srcOff[q] = cr * NN + ((jj ^ (cr & 3)) << 3);   // elements
    ldsOff[q] = (q * 256 + w * 64) << 3;            // elements, wave-uniform
  }

  // Pl write byte offsets (one per head); row = hh*32+pr
  int plw[2];
  #pragma unroll
  for (int hh = 0; hh < 2; ++hh) {
    int row = hh * 32 + pr;
    plw[hh] = (row * 64 + pk * 2) ^ ((row & 3) << 4);
  }
  // MFMA read byte offsets
  const int arow = hw * 32 + iw * 16 + (lane & 15);
  const int aoff = (arow * 64 + (lane >> 4) * 16) ^ ((arow & 3) << 4);
  int boff[4];
  #pragma unroll
  for (int cb = 0; cb < 4; ++cb) {
    int brow = hw * 64 + cb * 16 + (lane & 15);
    boff[cb] = (brow * 64 + (lane >> 4) * 16) ^ ((brow & 3) << 4);
  }

  f32x4 acc[4] = {};
  float den0 = 0.f, den1 = 0.f;

  const float* Ap  = A   + (size_t)(ib + pr) * NN + k0 + pk;
  const float* Xq0 = x1g + k0 + pk;
  const float* Xq1 = x1g + NN + k0 + pk;
  const int nt = KS >> 5;

  // --- prologue: tile-0 regs + stage B(0) into buf0 ---
  float4 aC  = *(const float4*)(Ap);
  float4 xC0 = *(const float4*)(Xq0);
  float4 xC1 = *(const float4*)(Xq1);
  {
    const ushort_t* s = XpT + k0;
    gload16(s + srcOff[0], Bl + ldsOff[0]);
    gload16(s + srcOff[1], Bl + ldsOff[1]);
  }
  float4 aN = aC, xN0 = xC0, xN1 = xC1;

  for (int tt = 0; tt < nt; ++tt) {
    const int par = tt & 1;
    const bool pf = (tt + 1 < nt);

    // prefetch next A / x1 into regs (3 vmem)
    if (pf) {
      aN  = *(const float4*)(Ap  + ((tt + 1) << 5));
      xN0 = *(const float4*)(Xq0 + ((tt + 1) << 5));
      xN1 = *(const float4*)(Xq1 + ((tt + 1) << 5));
    }

    // ---- P compute (both heads, 4 k each) from cur regs ----
    float av[4]  = {aC.x, aC.y, aC.z, aC.w};
    float x1a[4] = {xC0.x, xC0.y, xC0.z, xC0.w};
    float x1b[4] = {xC1.x, xC1.y, xC1.z, xC1.w};
    float p0[4], p1[4];
    #pragma unroll
    for (int j = 0; j < 4; ++j) {
      float s0 = x0v.x + x1a[j];
      p0[j] = av[j] * fexp2(fmaxf(s0, 0.2f * s0));
      den0 += p0[j];
      float s1 = x0v.y + x1b[j];
      p1[j] = av[j] * fexp2(fmaxf(s1, 0.2f * s1));
      den1 += p1[j];
    }
    uint_t u00, u01, u10, u11;
    asm("v_cvt_pk_bf16_f32 %0, %1, %2" : "=v"(u00) : "v"(p0[0]), "v"(p0[1]));
    asm("v_cvt_pk_bf16_f32 %0, %1, %2" : "=v"(u01) : "v"(p0[2]), "v"(p0[3]));
    asm("v_cvt_pk_bf16_f32 %0, %1, %2" : "=v"(u10) : "v"(p1[0]), "v"(p1[1]));
    asm("v_cvt_pk_bf16_f32 %0, %1, %2" : "=v"(u11) : "v"(p1[2]), "v"(p1[3]));
    uint2 v0; v0.x = u00; v0.y = u01;
    uint2 v1; v1.x = u10; v1.y = u11;

    // ---- barrier A: all waves done reading Pl(t-1) and Bl[par^1] ----
    asm volatile("s_waitcnt lgkmcnt(0)" ::: "memory");
    __builtin_amdgcn_s_barrier();
    asm volatile("" ::: "memory");

    // stage B(t+1) into the buffer MFMA(t) does not read (2 vmem)
    if (pf) {
      const ushort_t* s = XpT + k0 + ((tt + 1) << 5);
      ushort_t* d = Bl + (par ^ 1) * 4096;
      gload16(s + srcOff[0], d + ldsOff[0]);
      gload16(s + srcOff[1], d + ldsOff[1]);
    }

    // write Pl(t)
    *(uint2*)((char*)Pl + plw[0]) = v0;
    *(uint2*)((char*)Pl + plw[1]) = v1;

    // ---- barrier B: Pl(t) written; B(t) staged (counted vmcnt) ----
    if (pf) asm volatile("s_waitcnt vmcnt(5) lgkmcnt(0)" ::: "memory");
    else    asm volatile("s_waitcnt vmcnt(0) lgkmcnt(0)" ::: "memory");
    __builtin_amdgcn_s_barrier();
    asm volatile("" ::: "memory");

    // ---- MFMA on tile t ----
    const char* BlC = (const char*)(Bl + par * 4096);
    short8 af = *(const short8*)((const char*)Pl + aoff);
    #pragma unroll
    for (int cb = 0; cb < 4; ++cb) {
      short8 bv = *(const short8*)(BlC + boff[cb]);
      acc[cb] = __builtin_amdgcn_mfma_f32_16x16x32_bf16(af, bv, acc[cb], 0, 0, 0);
    }

    if (pf) { aC = aN; xC0 = xN0; xC1 = xN1; }
  }

  // --- den: reduce the 8 k-threads per row (width-8 butterfly) ---
  den0 += __shfl_xor(den0, 1, 8);
  den0 += __shfl_xor(den0, 2, 8);
  den0 += __shfl_xor(den0, 4, 8);
  den1 += __shfl_xor(den1, 1, 8);
  den1 += __shfl_xor(den1, 2, 8);
  den1 += __shfl_xor(den1, 4, 8);
  if ((t & 7) == 0) {
    float2 dv; dv.x = den0; dv.y = den1;
    *(float2*)(denp + ((size_t)sp * NN + ib + pr) * 2) = dv;
  }

  // --- partial numerators (C/D layout: col=lane&15, row=(lane>>4)*4+r) ---
  float* pbase = part + ((size_t)sp * NN + ib) * 128;
  #pragma unroll
  for (int cb = 0; cb < 4; ++cb) {
    #pragma unroll
    for (int r = 0; r < 4; ++r) {
      int lr  = iw * 16 + (lane >> 4) * 4 + r;
      int col = hw * 64 + cb * 16 + (lane & 15);
      pbase[lr * 128 + col] = acc[cb][r];
    }
  }
}

// ---------------------------------------------------------------------------
// K3: combine splits, normalize, add bias.
// ---------------------------------------------------------------------------
__global__ __launch_bounds__(256) void k3_finish(
    const float* __restrict__ part, const float* __restrict__ denp,
    const float* __restrict__ bias, float* __restrict__ out, const int S)
{
  const int idx = blockIdx.x * 256 + threadIdx.x;
  const int i  = idx >> 5;
  const int hc = (idx & 31) * 4;
  const int h  = hc >> 6;
  float4 s; s.x = s.y = s.z = s.w = 0.f;
  float d = 0.f;
  for (int sp = 0; sp < S; ++sp) {
    float4 v = *(const float4*)(part + ((size_t)sp * NN + i) * 128 + hc);
    s.x += v.x; s.y += v.y; s.z += v.z; s.w += v.w;
    d += denp[((size_t)sp * NN + i) * 2 + h];
  }
  const float sc = 1.f / (d + 0.001f);
  float4 bv = *(const float4*)(bias + hc);
  float4 o;
  o.x = s.x * sc + bv.x;
  o.y = s.y * sc + bv.y;
  o.z = s.z * sc + bv.z;
  o.w = s.w * sc + bv.w;
  *(float4*)(out + (size_t)i * 128 + hc) = o;
}

extern "C" void kernel_launch(void* const* d_in, const int* in_sizes, int n_in,
                              void* d_out, int out_size, void* d_ws, size_t ws_size,
                              hipStream_t stream) {
  const float* A    = (const float*)d_in[0];
  const float* X    = (const float*)d_in[1];
  const float* W    = (const float*)d_in[2];
  const float* attn = (const float*)d_in[3];
  const float* bias = (const float*)d_in[4];
  float* out = (float*)d_out;

  char* ws = (char*)d_ws;
  size_t off = 0;
  ushort_t* XpT = (ushort_t*)(ws + off); off += (size_t)128 * NN * sizeof(ushort_t);
  float* x0g = (float*)(ws + off); off += (size_t)NN * 2 * sizeof(float);
  float* x1g = (float*)(ws + off); off += (size_t)2 * NN * sizeof(float);

  int S = 8;   // split sp -> XCD sp (b%8): XpT slice L2-local per XCD
  while (S > 1) {
    size_t need = off + (size_t)S * NN * 2 * 4 + (size_t)S * NN * 128 * 4;
    if (need <= ws_size) break;
    S >>= 1;
  }
  float* denp = (float*)(ws + off); off += (size_t)S * NN * 2 * sizeof(float);
  float* part = (float*)(ws + off);
  const int KS = NN / S;

  k1_project<<<256, 256, 0, stream>>>(X, W, attn, XpT, x0g, x1g);
  k2_main<<<256 * S, 256, 0, stream>>>(A, XpT, x0g, x1g, part, denp, S, KS);
  k3_finish<<<1024, 256, 0, stream>>>(part, denp, bias, out, S);
}

// Round 11
// 106.827 us; speedup vs baseline: 2.0753x; 1.2483x over previous
//
#include <hip/hip_runtime.h>
#include <hip/hip_bf16.h>

typedef unsigned short ushort_t;
typedef unsigned int uint_t;
using f32x4  = __attribute__((ext_vector_type(4))) float;
using short8 = __attribute__((ext_vector_type(8))) short;

#define NN 8192
#define INVLN2 1.4426950408889634f

__device__ __forceinline__ ushort_t f2bf(float f) {
  uint_t u = __builtin_bit_cast(uint_t, f);
  u += 0x7FFFu + ((u >> 16) & 1u);   // RNE
  return (ushort_t)(u >> 16);
}

__device__ __forceinline__ float fexp2(float x) {
  float r; asm("v_exp_f32 %0, %1" : "=v"(r) : "v"(x)); return r;
}

__device__ __forceinline__ void gload16(const void* g, void* l) {
  __builtin_amdgcn_global_load_lds(
      (const __attribute__((address_space(1))) void*)g,
      (__attribute__((address_space(3))) void*)l, 16, 0, 0);
}

// ---------------------------------------------------------------------------
// K1: Xp = X @ W  -> XpT bf16 [2*64][8192] (row = h*64+c), x0[N][2], x1T[2][N]
// x0/x1 pre-scaled by 1/ln2 (lrelu positively homogeneous -> exp via exp2).
// (verified r8-r10)
// ---------------------------------------------------------------------------
__global__ __launch_bounds__(256, 2) void k1_project(
    const float* __restrict__ X, const float* __restrict__ W,
    const float* __restrict__ attn,
    ushort_t* __restrict__ XpT, float* __restrict__ x0g, float* __restrict__ x1g)
{
  __shared__ float    Xl[32][128];      // 16 KB
  __shared__ ushort_t XpL[128][56];     // 14 KB
  __shared__ float    P0[128][33];
  __shared__ float    P1[128][33];
  const int t  = threadIdx.x;
  const int nb = blockIdx.x * 32;

  #pragma unroll
  for (int r = 0; r < 4; ++r) {
    int chunk = r * 256 + t;
    ((float4*)(&Xl[0][0]))[chunk] = ((const float4*)(X + (size_t)nb * 128))[chunk];
  }
  __syncthreads();

  const int p = t & 127;
  const int g = t >> 7;
  const int h = p & 1, c = p >> 1;

  float acc[16];
  #pragma unroll
  for (int n = 0; n < 16; ++n) acc[n] = 0.f;

  for (int jc = 0; jc < 4; ++jc) {
    float wreg[32];
    #pragma unroll
    for (int jj = 0; jj < 32; ++jj) wreg[jj] = W[(jc * 32 + jj) * 128 + p];
    #pragma unroll
    for (int n = 0; n < 16; ++n) {
      const float4* xr = (const float4*)(&Xl[g * 16 + n][jc * 32]);
      float s = acc[n];
      #pragma unroll
      for (int q = 0; q < 8; ++q) {
        float4 xv = xr[q];
        s += xv.x * wreg[q*4+0] + xv.y * wreg[q*4+1] + xv.z * wreg[q*4+2] + xv.w * wreg[q*4+3];
      }
      acc[n] = s;
    }
  }

  const float a0 = attn[p] * INVLN2;
  const float a1 = attn[128 + p] * INVLN2;
  const int   row = h * 64 + c;
  #pragma unroll
  for (int n = 0; n < 16; ++n) {
    P0[p][g * 16 + n]  = acc[n] * a0;
    P1[p][g * 16 + n]  = acc[n] * a1;
    XpL[row][g * 16 + n] = f2bf(acc[n]);
  }
  __syncthreads();

  if (t < 128) {
    ushort_t* dst = XpT + (size_t)t * NN + nb;
    const uint4* src = (const uint4*)(&XpL[t][0]);
    ((uint4*)dst)[0] = src[0];
    ((uint4*)dst)[1] = src[1];
    ((uint4*)dst)[2] = src[2];
    ((uint4*)dst)[3] = src[3];
  }
  if (t < 64) {
    int node = t >> 1, hh = t & 1;
    float s0 = 0.f, s1 = 0.f;
    #pragma unroll
    for (int cc = 0; cc < 64; ++cc) {
      s0 += P0[cc * 2 + hh][node];
      s1 += P1[cc * 2 + hh][node];
    }
    x0g[(nb + node) * 2 + hh] = s0;
    x1g[hh * NN + nb + node]  = s1;
  }
}

// ---------------------------------------------------------------------------
// K2: BI=64 rows, K-step 32. Same barrier-pair count and occupancy as r3
// (1024 blocks x 32 bodies, 4 blocks/CU) but each B-frag ds_read feeds TWO
// A-row-blocks: 6 ds_read_b128 per 8 MFMA (0.75 KB/MFMA vs r3's 1.25).
// LDS = Pl 8 KB (single) + Bl 16 KB (dbuf) = 24 KB. Staging/swizzle for
// 64B rows verbatim from r10 (passed); barrier pair + counted vmcnt from r3.
// vmcnt(6) = this body's 4 reg-prefetch + 2 gload_lds in flight.
// S=8: split sp -> XCD sp (b%8), XpT slice L2-local.
// ---------------------------------------------------------------------------
__global__ __launch_bounds__(256, 4) void k2_main(
    const float* __restrict__ A, const ushort_t* __restrict__ XpT,
    const float* __restrict__ x0g, const float* __restrict__ x1g,
    float* __restrict__ part, float* __restrict__ denp,
    const int S, const int KS)
{
  __shared__ __align__(16) ushort_t Pl[128 * 32];       // 8 KB: 2h x 64 rows x 32k
  __shared__ __align__(16) ushort_t Bl[2 * 128 * 32];   // 16 KB double buffer
  const int t  = threadIdx.x;
  const int b  = blockIdx.x;
  const int rb = b / S, sp = b % S;
  const int ib = rb * 64;
  const int k0 = sp * KS;
  const int lane = t & 63, w = t >> 6;
  const int hw = w & 1, rh = w >> 1;    // wave: head, 32-row half
  const int l15 = lane & 15, lg = lane >> 4;
  const int pr = t >> 3;                // P-compute row 0..31 (ps adds +32)
  const int pk = (t & 7) * 4;           // P-compute k elem 0..28

  const float2 x0v0 = *(const float2*)(x0g + (ib + pr) * 2);
  const float2 x0v1 = *(const float2*)(x0g + (ib + 32 + pr) * 2);

  // B staging (r10 verbatim): chunk c=q*256+t; row=c>>2, granule jj=c&3.
  // LDS linear dest; source granule inverse-swizzled.
  int srcOff[2], ldsOff[2];
  #pragma unroll
  for (int q = 0; q < 2; ++q) {
    int c = q * 256 + t;
    int cr = c >> 2, jj = c & 3;
    srcOff[q] = cr * NN + ((jj ^ (cr & 3)) << 3);   // elements
    ldsOff[q] = (q * 256 + w * 64) << 3;            // elements, wave-uniform
  }

  // Pl write byte offsets [ps][hh]; row = hh*64 + ps*32 + pr (row&3 == pr&3)
  int plw[2][2];
  #pragma unroll
  for (int ps = 0; ps < 2; ++ps)
    #pragma unroll
    for (int hh = 0; hh < 2; ++hh) {
      int row = hh * 64 + ps * 32 + pr;
      plw[ps][hh] = (row * 64 + pk * 2) ^ ((pr & 3) << 4);
    }

  // MFMA read byte offsets (64B rows, ^((row&3)<<4) swizzle)
  int aoff[2];
  #pragma unroll
  for (int iwi = 0; iwi < 2; ++iwi) {
    int arow = hw * 64 + rh * 32 + iwi * 16 + l15;
    aoff[iwi] = (arow * 64 + lg * 16) ^ ((arow & 3) << 4);
  }
  int boff[4];
  #pragma unroll
  for (int cb = 0; cb < 4; ++cb) {
    int brow = hw * 64 + cb * 16 + l15;
    boff[cb] = (brow * 64 + lg * 16) ^ ((brow & 3) << 4);
  }

  f32x4 acc[2][4] = {};
  float den[2][2] = {};

  const float* Ap0 = A + (size_t)(ib + pr) * NN + k0 + pk;
  const float* Ap1 = A + (size_t)(ib + 32 + pr) * NN + k0 + pk;
  const float* Xq0 = x1g + k0 + pk;
  const float* Xq1 = x1g + NN + k0 + pk;
  const int nt = KS >> 5;

  // --- prologue: tile-0 regs + stage B(0) into buf0 ---
  float4 aC0 = *(const float4*)(Ap0);
  float4 aC1 = *(const float4*)(Ap1);
  float4 xC0 = *(const float4*)(Xq0);
  float4 xC1 = *(const float4*)(Xq1);
  {
    const ushort_t* s = XpT + k0;
    gload16(s + srcOff[0], Bl + ldsOff[0]);
    gload16(s + srcOff[1], Bl + ldsOff[1]);
  }
  float4 aN0 = aC0, aN1 = aC1, xN0 = xC0, xN1 = xC1;

  for (int tt = 0; tt < nt; ++tt) {
    const int par = tt & 1;
    const bool pf = (tt + 1 < nt);

    // prefetch next A / x1 into regs (4 vmem)
    if (pf) {
      aN0 = *(const float4*)(Ap0 + ((tt + 1) << 5));
      aN1 = *(const float4*)(Ap1 + ((tt + 1) << 5));
      xN0 = *(const float4*)(Xq0 + ((tt + 1) << 5));
      xN1 = *(const float4*)(Xq1 + ((tt + 1) << 5));
    }

    // ---- P compute: 2 row-halves x 2 heads x 4 k ----
    float a0v[4] = {aC0.x, aC0.y, aC0.z, aC0.w};
    float a1v[4] = {aC1.x, aC1.y, aC1.z, aC1.w};
    float x1a[4] = {xC0.x, xC0.y, xC0.z, xC0.w};
    float x1b[4] = {xC1.x, xC1.y, xC1.z, xC1.w};
    uint2 pv[2][2];
    #pragma unroll
    for (int ps = 0; ps < 2; ++ps) {
      const float* av = ps ? a1v : a0v;
      const float2 xv = ps ? x0v1 : x0v0;
      #pragma unroll
      for (int hh = 0; hh < 2; ++hh) {
        const float* x1v = hh ? x1b : x1a;
        const float x0s = hh ? xv.y : xv.x;
        float p[4];
        #pragma unroll
        for (int j = 0; j < 4; ++j) {
          float s = x0s + x1v[j];
          p[j] = av[j] * fexp2(fmaxf(s, 0.2f * s));
          den[ps][hh] += p[j];
        }
        uint_t u0, u1;
        asm("v_cvt_pk_bf16_f32 %0, %1, %2" : "=v"(u0) : "v"(p[0]), "v"(p[1]));
        asm("v_cvt_pk_bf16_f32 %0, %1, %2" : "=v"(u1) : "v"(p[2]), "v"(p[3]));
        pv[ps][hh].x = u0; pv[ps][hh].y = u1;
      }
    }

    // ---- barrier A: all waves done reading Pl(t-1) and Bl[par^1] ----
    asm volatile("s_waitcnt lgkmcnt(0)" ::: "memory");
    __builtin_amdgcn_s_barrier();
    asm volatile("" ::: "memory");

    // stage B(t+1) into the buffer MFMA(t) does not read (2 vmem)
    if (pf) {
      const ushort_t* s = XpT + k0 + ((tt + 1) << 5);
      ushort_t* d = Bl + (par ^ 1) * 4096;
      gload16(s + srcOff[0], d + ldsOff[0]);
      gload16(s + srcOff[1], d + ldsOff[1]);
    }

    // write Pl(t)
    #pragma unroll
    for (int ps = 0; ps < 2; ++ps)
      #pragma unroll
      for (int hh = 0; hh < 2; ++hh)
        *(uint2*)((char*)Pl + plw[ps][hh]) = pv[ps][hh];

    // ---- barrier B: Pl(t) written; B(t) staged (counted vmcnt) ----
    if (pf) asm volatile("s_waitcnt vmcnt(6) lgkmcnt(0)" ::: "memory");
    else    asm volatile("s_waitcnt vmcnt(0) lgkmcnt(0)" ::: "memory");
    __builtin_amdgcn_s_barrier();
    asm volatile("" ::: "memory");

    // ---- MFMA on tile t: 6 ds_read_b128, 8 MFMA (B reused across iwi) ----
    const char* BlC = (const char*)(Bl + par * 4096);
    short8 af0 = *(const short8*)((const char*)Pl + aoff[0]);
    short8 af1 = *(const short8*)((const char*)Pl + aoff[1]);
    #pragma unroll
    for (int cb = 0; cb < 4; ++cb) {
      short8 bv = *(const short8*)(BlC + boff[cb]);
      acc[0][cb] = __builtin_amdgcn_mfma_f32_16x16x32_bf16(af0, bv, acc[0][cb], 0, 0, 0);
      acc[1][cb] = __builtin_amdgcn_mfma_f32_16x16x32_bf16(af1, bv, acc[1][cb], 0, 0, 0);
    }

    if (pf) { aC0 = aN0; aC1 = aN1; xC0 = xN0; xC1 = xN1; }
  }

  // --- den: reduce the 8 k-threads per row (width-8 butterfly) ---
  #pragma unroll
  for (int ps = 0; ps < 2; ++ps) {
    float d0 = den[ps][0], d1 = den[ps][1];
    d0 += __shfl_xor(d0, 1, 8); d0 += __shfl_xor(d0, 2, 8); d0 += __shfl_xor(d0, 4, 8);
    d1 += __shfl_xor(d1, 1, 8); d1 += __shfl_xor(d1, 2, 8); d1 += __shfl_xor(d1, 4, 8);
    if ((t & 7) == 0) {
      float2 dv; dv.x = d0; dv.y = d1;
      *(float2*)(denp + ((size_t)sp * NN + ib + ps * 32 + pr) * 2) = dv;
    }
  }

  // --- partial numerators (C/D layout: col=lane&15, row=(lane>>4)*4+r) ---
  float* pbase = part + ((size_t)sp * NN + ib) * 128;
  #pragma unroll
  for (int iwi = 0; iwi < 2; ++iwi)
    #pragma unroll
    for (int cb = 0; cb < 4; ++cb)
      #pragma unroll
      for (int r = 0; r < 4; ++r) {
        int lr  = rh * 32 + iwi * 16 + lg * 4 + r;
        int col = hw * 64 + cb * 16 + l15;
        pbase[lr * 128 + col] = acc[iwi][cb][r];
      }
}

// ---------------------------------------------------------------------------
// K3: combine splits, normalize, add bias.
// ---------------------------------------------------------------------------
__global__ __launch_bounds__(256) void k3_finish(
    const float* __restrict__ part, const float* __restrict__ denp,
    const float* __restrict__ bias, float* __restrict__ out, const int S)
{
  const int idx = blockIdx.x * 256 + threadIdx.x;
  const int i  = idx >> 5;
  const int hc = (idx & 31) * 4;
  const int h  = hc >> 6;
  float4 s; s.x = s.y = s.z = s.w = 0.f;
  float d = 0.f;
  for (int sp = 0; sp < S; ++sp) {
    float4 v = *(const float4*)(part + ((size_t)sp * NN + i) * 128 + hc);
    s.x += v.x; s.y += v.y; s.z += v.z; s.w += v.w;
    d += denp[((size_t)sp * NN + i) * 2 + h];
  }
  const float sc = 1.f / (d + 0.001f);
  float4 bv = *(const float4*)(bias + hc);
  float4 o;
  o.x = s.x * sc + bv.x;
  o.y = s.y * sc + bv.y;
  o.z = s.z * sc + bv.z;
  o.w = s.w * sc + bv.w;
  *(float4*)(out + (size_t)i * 128 + hc) = o;
}

extern "C" void kernel_launch(void* const* d_in, const int* in_sizes, int n_in,
                              void* d_out, int out_size, void* d_ws, size_t ws_size,
                              hipStream_t stream) {
  const float* A    = (const float*)d_in[0];
  const float* X    = (const float*)d_in[1];
  const float* W    = (const float*)d_in[2];
  const float* attn = (const float*)d_in[3];
  const float* bias = (const float*)d_in[4];
  float* out = (float*)d_out;

  char* ws = (char*)d_ws;
  size_t off = 0;
  ushort_t* XpT = (ushort_t*)(ws + off); off += (size_t)128 * NN * sizeof(ushort_t);
  float* x0g = (float*)(ws + off); off += (size_t)NN * 2 * sizeof(float);
  float* x1g = (float*)(ws + off); off += (size_t)2 * NN * sizeof(float);

  int S = 8;   // split sp -> XCD sp (b%8): XpT slice L2-local per XCD
  while (S > 1) {
    size_t need = off + (size_t)S * NN * 2 * 4 + (size_t)S * NN * 128 * 4;
    if (need <= ws_size) break;
    S >>= 1;
  }
  float* denp = (float*)(ws + off); off += (size_t)S * NN * 2 * sizeof(float);
  float* part = (float*)(ws + off);
  const int KS = NN / S;

  k1_project<<<256, 256, 0, stream>>>(X, W, attn, XpT, x0g, x1g);
  k2_main<<<(NN / 64) * S, 256, 0, stream>>>(A, XpT, x0g, x1g, part, denp, S, KS);
  k3_finish<<<1024, 256, 0, stream>>>(part, denp, bias, out, S);
}